// Round 6
// baseline (231.506 us; speedup 1.0000x reference)
//
#include <hip/hip_runtime.h>
#include <cstdint>

typedef _Float16 half8 __attribute__((ext_vector_type(8)));
typedef __fp16 fp16x2 __attribute__((ext_vector_type(2)));
typedef float f32x4 __attribute__((ext_vector_type(4)));

// ws layout (halfs), per head 2048*64 = 131072 per tensor:
//  Kt: [head] fragment-order: frag(st=s/16, ks) at (st*2+ks)*512 + lane*8,
//      lane(q,l15) 8 halfs = K[16st+l15][32ks+8q+j]           (A-frag for S^T)
//  Vt: [head] sigma-fragment-order: frag(sc=s/32, ct) at (sc*4+ct)*512 + lane*8,
//      lane(q,l15) 8 halfs j = V[16ct+l15][32sc+4q+(j&3)+16(j>>2)]  (A-frag for O)
#define HSTRIDE 131072
#define KOFF    ((size_t)64 * HSTRIDE)
#define VOFF    ((size_t)128 * HSTRIDE)

__device__ __forceinline__ float fast_exp2(float x) {
    return __builtin_amdgcn_exp2f(x);
}

__device__ __forceinline__ uint32_t pkrtz(float a, float b) {
    fp16x2 h = __builtin_amdgcn_cvt_pkrtz(a, b);
    return __builtin_bit_cast(uint32_t, h);
}

// ---------------- prep: K transpose + V sigma-pack (unchanged) ----------------
__global__ __launch_bounds__(256) void prep_kernel(const float* __restrict__ qkv,
                                                   _Float16* __restrict__ ws)
{
    __shared__ float Lf[64 * 67];        // 16.75 KB (K branch only)

    const int tid  = threadIdx.x;
    const int lane = tid & 63;
    const int wave = tid >> 6;
    const int bid  = blockIdx.x;

    if (bid < 2048) {
        // ---- K ----
        const int head  = (bid >> 5) & 63;
        const int chunk = bid & 31;          // 64-wide s chunk
        const int b4 = head >> 4, h = head & 15;
        const float* src = qkv + (((size_t)(b4 * 3072 + h * 192 + 64)) << 11)
                         + chunk * 64;

#pragma unroll
        for (int k = 0; k < 4; ++k) {
            int idx = k * 256 + tid;
            int c = idx >> 4;
            int t4 = (idx & 15) << 2;
            float4 f = *(const float4*)&src[(((size_t)c) << 11) + t4];
            float* d = &Lf[c * 67 + t4];
            d[0] = f.x; d[1] = f.y; d[2] = f.z; d[3] = f.w;
        }
        __syncthreads();

        const int q = lane >> 4, l15 = lane & 15;
        const int scol = wave * 16 + l15;    // s within chunk
#pragma unroll
        for (int k = 0; k < 2; ++k) {
            uint32_t d[4];
#pragma unroll
            for (int j = 0; j < 4; ++j) {
                float a = Lf[(32 * k + 8 * q + 2 * j) * 67 + scol];
                float b = Lf[(32 * k + 8 * q + 2 * j + 1) * 67 + scol];
                d[j] = pkrtz(a, b);
            }
            size_t off = KOFF + (size_t)head * HSTRIDE
                       + (size_t)((((chunk * 4 + wave) * 2 + k) * 512) + lane * 8);
            *(uint4*)&ws[off] = make_uint4(d[0], d[1], d[2], d[3]);
        }
    } else {
        // ---- V ----
        const int vb = bid - 2048;
        const int head = vb >> 5, chunk = vb & 31;   // 64-s chunk
        const int b4 = head >> 4, h = head & 15;
        const float* src = qkv + (((size_t)(b4 * 3072 + h * 192 + 128)) << 11) + chunk * 64;
        const int q = lane >> 4, cl = lane & 15;
        const int c = wave * 16 + cl;
#pragma unroll
        for (int k = 0; k < 2; ++k) {
            const float* p = &src[((size_t)c << 11) + k * 32 + q * 4];
            float4 f0 = *(const float4*)&p[0];      // s = 4q..4q+3   (j=0..3)
            float4 f1 = *(const float4*)&p[16];     // s = 16+4q..+3  (j=4..7)
            size_t off = VOFF + (size_t)head * HSTRIDE
                       + (size_t)(((chunk * 2 + k) * 4 + wave) * 512 + lane * 8);
            *(uint4*)&ws[off] = make_uint4(pkrtz(f0.x, f0.y), pkrtz(f0.z, f0.w),
                                           pkrtz(f1.x, f1.y), pkrtz(f1.z, f1.w));
        }
    }
}

// ---------------- flash attention: 4 waves/SIMD via fine t-split ----------------
// Round-14. Rounds 9-13: FIVE structures all give MfmaUtil ~38-40 +
// VALUBusy ~35-37 SUMMING -> accepted model: on CDNA4 a SIMD's MFMA and
// VALU/TRANS occupancies are ADDITIVE (shared issue/exec port). Cross-check:
// AITER fmha d=128 has exp-work ~25-30% of MFMA work and tops out at 76%
// MfmaUtil = the additive ceiling. Interleaving is therefore useless; the
// ~25% idle issue slots (dependency/VMEM gaps with only 2 waves/SIMD) are
// the remaining lever -> raise occupancy to 4 waves/SIMD: nt=2 (32 t/wave,
// 128 t/block), grid 1024 = 4 blocks/CU x 4 waves. Body reverted to the
// round-12 form (r13's rotation regressed; SGBs dropped). Lacc back to
// VALU adds + shfl epilogue (round-8 numerics): -2 MFMA +16 VALU per tile
// (net win) and -12 VGPR. launch_bounds(256,4) caps VGPR at 128.
// K/V L2 traffic doubles (16 passes of 0.5 MB/head) ~7 TB/s << 34 TB/s;
// HBM unchanged (L3 absorbs).
__launch_bounds__(256, 4)
__global__ void attn_kernel(const float* __restrict__ qkv,
                            const _Float16* __restrict__ ws, float* __restrict__ out)
{
    const int tid  = threadIdx.x;
    const int lane = tid & 63;
    const int wave = tid >> 6;
    const int l15  = lane & 15;
    const int quad = lane >> 4;

    const int bid  = blockIdx.x;
    const int head = bid & 63;          // grid = 16 tblk x 64 head
    const int tblk = bid >> 6;          // 0..15
    const int T0   = tblk * 128;        // block covers 128 t; wave covers 32 t
    const int b4   = head >> 4;
    const int h    = head & 15;

    // per-lane fragment base pointers (lane*8 halfs = 16B slice)
    const _Float16* Kt = ws + KOFF + (size_t)head * HSTRIDE + lane * 8;
    const _Float16* Vt = ws + VOFF + (size_t)head * HSTRIDE + lane * 8;
    const float*    Qg = qkv + ((size_t)(b4 * 3072 + h * 192) << 11);
    const float kQ = 0.125f * 1.44269504088896340736f;  // scale^2 * log2(e)

    f32x4 Oacc[4][2];
#pragma unroll
    for (int ct = 0; ct < 4; ++ct)
#pragma unroll
        for (int nt = 0; nt < 2; ++nt) Oacc[ct][nt] = (f32x4)0.f;
    float lacc[2] = {0.f, 0.f};
    const f32x4 fz = (f32x4)0.f;

    // K/V fragment register dbufs. Tile i (32-s): K frags (4i+st*2+ks)*512,
    // V frags (4i+ct)*512.
    half8 kfA[2][2], kfB[2][2], vfA[4], vfB[4];

    // prologue: tiles 0 (A) and 1 (B) in flight before the Q gather
#pragma unroll
    for (int st = 0; st < 2; ++st)
#pragma unroll
        for (int ks = 0; ks < 2; ++ks) {
            kfA[st][ks] = *(const half8*)(Kt + (size_t)(0 * 4 + st * 2 + ks) * 512);
            kfB[st][ks] = *(const half8*)(Kt + (size_t)(1 * 4 + st * 2 + ks) * 512);
        }
#pragma unroll
    for (int ct = 0; ct < 4; ++ct) {
        vfA[ct] = *(const half8*)(Vt + (size_t)(0 * 4 + ct) * 512);
        vfB[ct] = *(const half8*)(Vt + (size_t)(1 * 4 + ct) * 512);
    }

    // Q B-frags: B[k=c=32ks+8q+j][n=t=16nt+l15], direct fp32 gather + scale + pack.
    half8 qb[2][2];
#pragma unroll
    for (int nt = 0; nt < 2; ++nt) {
        const int t = T0 + wave * 32 + nt * 16 + l15;
#pragma unroll
        for (int ks = 0; ks < 2; ++ks) {
            float f[8];
#pragma unroll
            for (int j = 0; j < 8; ++j)
                f[j] = Qg[((size_t)(ks * 32 + quad * 8 + j) << 11) + t];
            uint4 u = make_uint4(pkrtz(f[0] * kQ, f[1] * kQ), pkrtz(f[2] * kQ, f[3] * kQ),
                                 pkrtz(f[4] * kQ, f[5] * kQ), pkrtz(f[6] * kQ, f[7] * kQ));
            qb[nt][ks] = __builtin_bit_cast(half8, u);
        }
    }

    half8 pf[2];   // P B-frags of tile i, consumed by O(i) in body(i+1)

    // S(0) -> exp -> pf (+ lacc)
    {
        f32x4 Sa[2], Sb[2];
#pragma unroll
        for (int nt = 0; nt < 2; ++nt) {
            f32x4 t0 = __builtin_amdgcn_mfma_f32_16x16x32_f16(kfA[0][0], qb[nt][0], fz, 0, 0, 0);
            Sa[nt]   = __builtin_amdgcn_mfma_f32_16x16x32_f16(kfA[0][1], qb[nt][1], t0, 0, 0, 0);
            f32x4 t1 = __builtin_amdgcn_mfma_f32_16x16x32_f16(kfA[1][0], qb[nt][0], fz, 0, 0, 0);
            Sb[nt]   = __builtin_amdgcn_mfma_f32_16x16x32_f16(kfA[1][1], qb[nt][1], t1, 0, 0, 0);
        }
#pragma unroll
        for (int nt = 0; nt < 2; ++nt) {
            float e0 = fast_exp2(Sa[nt][0]);
            float e1 = fast_exp2(Sa[nt][1]);
            float e2 = fast_exp2(Sa[nt][2]);
            float e3 = fast_exp2(Sa[nt][3]);
            float e4 = fast_exp2(Sb[nt][0]);
            float e5 = fast_exp2(Sb[nt][1]);
            float e6 = fast_exp2(Sb[nt][2]);
            float e7 = fast_exp2(Sb[nt][3]);
            lacc[nt] += ((e0 + e1) + (e2 + e3)) + ((e4 + e5) + (e6 + e7));
            uint4 u = make_uint4(pkrtz(e0, e1), pkrtz(e2, e3),
                                 pkrtz(e4, e5), pkrtz(e6, e7));
            pf[nt] = __builtin_bit_cast(half8, u);
        }
    }

    // body(i): [load kf(i+1) -> N] [O(i-1) consumes vfN(=vf(i-1)) + pf]
    //          [load vf(i+1) -> N] [S(i) from kfC -> exp -> pf, lacc]
    auto body = [&](int i, half8 (&kfC)[2][2], half8 (&kfN)[2][2],
                    half8 (&vfN)[4], bool pre) {
        if (pre) {
#pragma unroll
            for (int st = 0; st < 2; ++st)
#pragma unroll
                for (int ks = 0; ks < 2; ++ks)
                    kfN[st][ks] = *(const half8*)(Kt + (size_t)((i + 1) * 4 + st * 2 + ks) * 512);
        }
#pragma unroll
        for (int ct = 0; ct < 4; ++ct)
#pragma unroll
            for (int nt = 0; nt < 2; ++nt)
                Oacc[ct][nt] = __builtin_amdgcn_mfma_f32_16x16x32_f16(
                    vfN[ct], pf[nt], Oacc[ct][nt], 0, 0, 0);
        if (pre) {
#pragma unroll
            for (int ct = 0; ct < 4; ++ct)
                vfN[ct] = *(const half8*)(Vt + (size_t)((i + 1) * 4 + ct) * 512);
        }
        f32x4 Sa[2], Sb[2];
#pragma unroll
        for (int nt = 0; nt < 2; ++nt) {
            f32x4 t0 = __builtin_amdgcn_mfma_f32_16x16x32_f16(kfC[0][0], qb[nt][0], fz, 0, 0, 0);
            Sa[nt]   = __builtin_amdgcn_mfma_f32_16x16x32_f16(kfC[0][1], qb[nt][1], t0, 0, 0, 0);
            f32x4 t1 = __builtin_amdgcn_mfma_f32_16x16x32_f16(kfC[1][0], qb[nt][0], fz, 0, 0, 0);
            Sb[nt]   = __builtin_amdgcn_mfma_f32_16x16x32_f16(kfC[1][1], qb[nt][1], t1, 0, 0, 0);
        }
#pragma unroll
        for (int nt = 0; nt < 2; ++nt) {
            float e0 = fast_exp2(Sa[nt][0]);
            float e1 = fast_exp2(Sa[nt][1]);
            float e2 = fast_exp2(Sa[nt][2]);
            float e3 = fast_exp2(Sa[nt][3]);
            float e4 = fast_exp2(Sb[nt][0]);
            float e5 = fast_exp2(Sb[nt][1]);
            float e6 = fast_exp2(Sb[nt][2]);
            float e7 = fast_exp2(Sb[nt][3]);
            lacc[nt] += ((e0 + e1) + (e2 + e3)) + ((e4 + e5) + (e6 + e7));
            uint4 u = make_uint4(pkrtz(e0, e1), pkrtz(e2, e3),
                                 pkrtz(e4, e5), pkrtz(e6, e7));
            pf[nt] = __builtin_bit_cast(half8, u);
        }
    };

    // main loop: i = 1..62 (2x unrolled for static ping-pong), then i=63 no-load
    for (int m = 0; m < 31; ++m) {
        body(2 * m + 1, kfB, kfA, vfA, true);    // odd i: cur=B, N=A (holds i-1; reload i+1)
        body(2 * m + 2, kfA, kfB, vfB, true);    // even i: cur=A, N=B
    }
    body(63, kfB, kfA, vfA, false);

    // tail: O(63) with vf(63)=vfB and pf(63)
#pragma unroll
    for (int ct = 0; ct < 4; ++ct)
#pragma unroll
        for (int nt = 0; nt < 2; ++nt)
            Oacc[ct][nt] = __builtin_amdgcn_mfma_f32_16x16x32_f16(
                vfB[ct], pf[nt], Oacc[ct][nt], 0, 0, 0);

    // ---- epilogue: reduce lacc across quads (rows of S live in quads) ----
    float inv[2];
#pragma unroll
    for (int nt = 0; nt < 2; ++nt) {
        float v = lacc[nt];
        v += __shfl_xor(v, 16, 64);
        v += __shfl_xor(v, 32, 64);
        inv[nt] = 1.f / v;
    }

    float* ob = out + (((size_t)(b4 * 1024 + h * 64)) << 11) + T0 + wave * 32;
#pragma unroll
    for (int ct = 0; ct < 4; ++ct)
#pragma unroll
        for (int nt = 0; nt < 2; ++nt) {
            f32x4 o = Oacc[ct][nt];
#pragma unroll
            for (int r = 0; r < 4; ++r)
                ob[((size_t)(ct * 16 + quad * 4 + r) << 11) + nt * 16 + l15] = o[r] * inv[nt];
        }
}

extern "C" void kernel_launch(void* const* d_in, const int* in_sizes, int n_in,
                              void* d_out, int out_size, void* d_ws, size_t ws_size,
                              hipStream_t stream) {
    const float* qkv = (const float*)d_in[0];
    float* out = (float*)d_out;
    _Float16* ws = (_Float16*)d_ws;
    prep_kernel<<<dim3(4096), dim3(256), 0, stream>>>(qkv, ws);
    attn_kernel<<<dim3(1024), dim3(256), 0, stream>>>(qkv, ws, out);
}

// Round 7
// 219.059 us; speedup vs baseline: 1.0568x; 1.0568x over previous
//
#include <hip/hip_runtime.h>
#include <cstdint>

typedef _Float16 half8 __attribute__((ext_vector_type(8)));
typedef __fp16 fp16x2 __attribute__((ext_vector_type(2)));
typedef float f32x4 __attribute__((ext_vector_type(4)));

// ws layout (halfs), per head 2048*64 = 131072 per tensor:
//  Kt: [head] fragment-order: frag(st=s/16, ks) at (st*2+ks)*512 + lane*8,
//      lane(q,l15) 8 halfs = K[16st+l15][32ks+8q+j]           (A-frag for S^T)
//  Vt: [head] sigma-fragment-order: frag(sc=s/32, ct) at (sc*4+ct)*512 + lane*8,
//      lane(q,l15) 8 halfs j = V[16ct+l15][32sc+4q+(j&3)+16(j>>2)]  (A-frag for O)
#define HSTRIDE 131072
#define KOFF    ((size_t)64 * HSTRIDE)
#define VOFF    ((size_t)128 * HSTRIDE)

__device__ __forceinline__ float fast_exp2(float x) {
    return __builtin_amdgcn_exp2f(x);
}

__device__ __forceinline__ uint32_t pkrtz(float a, float b) {
    fp16x2 h = __builtin_amdgcn_cvt_pkrtz(a, b);
    return __builtin_bit_cast(uint32_t, h);
}

__device__ __forceinline__ void load_lds16(const _Float16* g, _Float16* l) {
    auto* g1 = reinterpret_cast<const __attribute__((address_space(1))) uint32_t*>(
        reinterpret_cast<uintptr_t>(g));
    auto* l3 = reinterpret_cast<__attribute__((address_space(3))) uint32_t*>(
        reinterpret_cast<uintptr_t>(l));
    __builtin_amdgcn_global_load_lds(g1, l3, 16, 0, 0);
}

// ---------------- prep: K transpose + V sigma-pack (unchanged) ----------------
__global__ __launch_bounds__(256) void prep_kernel(const float* __restrict__ qkv,
                                                   _Float16* __restrict__ ws)
{
    __shared__ float Lf[64 * 67];        // 16.75 KB (K branch only)

    const int tid  = threadIdx.x;
    const int lane = tid & 63;
    const int wave = tid >> 6;
    const int bid  = blockIdx.x;

    if (bid < 2048) {
        // ---- K ----
        const int head  = (bid >> 5) & 63;
        const int chunk = bid & 31;          // 64-wide s chunk
        const int b4 = head >> 4, h = head & 15;
        const float* src = qkv + (((size_t)(b4 * 3072 + h * 192 + 64)) << 11)
                         + chunk * 64;

#pragma unroll
        for (int k = 0; k < 4; ++k) {
            int idx = k * 256 + tid;
            int c = idx >> 4;
            int t4 = (idx & 15) << 2;
            float4 f = *(const float4*)&src[(((size_t)c) << 11) + t4];
            float* d = &Lf[c * 67 + t4];
            d[0] = f.x; d[1] = f.y; d[2] = f.z; d[3] = f.w;
        }
        __syncthreads();

        const int q = lane >> 4, l15 = lane & 15;
        const int scol = wave * 16 + l15;    // s within chunk
#pragma unroll
        for (int k = 0; k < 2; ++k) {
            uint32_t d[4];
#pragma unroll
            for (int j = 0; j < 4; ++j) {
                float a = Lf[(32 * k + 8 * q + 2 * j) * 67 + scol];
                float b = Lf[(32 * k + 8 * q + 2 * j + 1) * 67 + scol];
                d[j] = pkrtz(a, b);
            }
            size_t off = KOFF + (size_t)head * HSTRIDE
                       + (size_t)((((chunk * 4 + wave) * 2 + k) * 512) + lane * 8);
            *(uint4*)&ws[off] = make_uint4(d[0], d[1], d[2], d[3]);
        }
    } else {
        // ---- V ----
        const int vb = bid - 2048;
        const int head = vb >> 5, chunk = vb & 31;   // 64-s chunk
        const int b4 = head >> 4, h = head & 15;
        const float* src = qkv + (((size_t)(b4 * 3072 + h * 192 + 128)) << 11) + chunk * 64;
        const int q = lane >> 4, cl = lane & 15;
        const int c = wave * 16 + cl;
#pragma unroll
        for (int k = 0; k < 2; ++k) {
            const float* p = &src[((size_t)c << 11) + k * 32 + q * 4];
            float4 f0 = *(const float4*)&p[0];      // s = 4q..4q+3   (j=0..3)
            float4 f1 = *(const float4*)&p[16];     // s = 16+4q..+3  (j=4..7)
            size_t off = VOFF + (size_t)head * HSTRIDE
                       + (size_t)(((chunk * 2 + k) * 4 + wave) * 512 + lane * 8);
            *(uint4*)&ws[off] = make_uint4(pkrtz(f0.x, f0.y), pkrtz(f0.z, f0.w),
                                           pkrtz(f1.x, f1.y), pkrtz(f1.z, f1.w));
        }
    }
}

// ---------------- flash attention: 8-wave blocks, LDS-shared, 4 waves/SIMD ----------------
// Round-15. r14's occupancy probe was confounded: no-LDS K/V streams are
// per-wave private, so 16 waves/CU demanded ~166 B/cyc/CU of L2 read BW vs
// ~56 available -> L2-bound, MfmaUtil fell to 30. The clean occupancy test
// keeps LDS sharing (8 KB/tile/BLOCK, ~10 B/cyc/CU): r9's proven
// triple-buffered pipeline, but 512-thread blocks (8 waves, nt=2 per wave),
// 512 blocks = 2 blocks/CU x 8 waves = 16 waves/CU = 4 waves/SIMD.
// Per-wave staging halves (1 global_load_lds each for K and V). Total MFMA,
// exp work, barrier structure, tile order and numerics identical to r9.
// Under the accepted additive issue-port model (5 structures all at
// MFMA+VALU ~77%, summing), 4 waves/SIMD should fill the ~23% idle issue
// slots left by dependency/VMEM gaps at 2 waves/SIMD.
// launch_bounds(512,4) caps VGPR at 128 (nt=2 state ~110).
__launch_bounds__(512, 4)
__global__ void attn_kernel(const float* __restrict__ qkv,
                            const _Float16* __restrict__ ws, float* __restrict__ out)
{
    __shared__ __align__(16) _Float16 sK[3][4096];   // 3 x 8 KB, fragment-linear
    __shared__ __align__(16) _Float16 sV[3][4096];   // 3 x 8 KB, fragment-linear

    const int tid  = threadIdx.x;
    const int lane = tid & 63;
    const int wave = tid >> 6;          // 0..7
    const int l15  = lane & 15;
    const int quad = lane >> 4;

    const int bid  = blockIdx.x;
    const int head = bid & 63;
    const int tblk = bid >> 6;          // 0..7
    const int T0   = tblk * 256;        // block covers 256 t; wave covers 32 t
    const int b4   = head >> 4;
    const int h    = head & 15;

    const _Float16* Kt = ws + KOFF + (size_t)head * HSTRIDE;
    const _Float16* Vt = ws + VOFF + (size_t)head * HSTRIDE;
    const float*    Qg = qkv + ((size_t)(b4 * 3072 + h * 192) << 11);
    const float kQ = 0.125f * 1.44269504088896340736f;  // scale^2 * log2(e)

    f32x4 Oacc[4][2];
#pragma unroll
    for (int ct = 0; ct < 4; ++ct)
#pragma unroll
        for (int nt = 0; nt < 2; ++nt) Oacc[ct][nt] = (f32x4)0.f;
    float lacc[2] = {0.f, 0.f};
    const f32x4 fz = (f32x4)0.f;

    const int lb = lane * 8;

    // 8-wave staging: each wave copies 1 KB of K and 1 KB of V (tile = 8 KB each)
    auto stage = [&](int buf, int tile) {
        const _Float16* kg = Kt + (size_t)tile * 4096 + wave * 512 + lane * 8;
        const _Float16* vg = Vt + (size_t)tile * 4096 + wave * 512 + lane * 8;
        load_lds16(kg, &sK[buf][wave * 512]);
        load_lds16(vg, &sV[buf][wave * 512]);
    };

    stage(0, 0);   // tiles 0 and 1 in flight before/under the Q gather
    stage(1, 1);

    // Q B-frags: B[k=c=32ks+8q+j][n=t=16nt+l15], direct fp32 gather + scale + pack.
    half8 qb[2][2];
#pragma unroll
    for (int nt = 0; nt < 2; ++nt) {
        const int t = T0 + wave * 32 + nt * 16 + l15;
#pragma unroll
        for (int ks = 0; ks < 2; ++ks) {
            float f[8];
#pragma unroll
            for (int j = 0; j < 8; ++j)
                f[j] = Qg[((size_t)(ks * 32 + quad * 8 + j) << 11) + t];
            uint4 u = make_uint4(pkrtz(f[0] * kQ, f[1] * kQ), pkrtz(f[2] * kQ, f[3] * kQ),
                                 pkrtz(f[4] * kQ, f[5] * kQ), pkrtz(f[6] * kQ, f[7] * kQ));
            qb[nt][ks] = __builtin_bit_cast(half8, u);
        }
    }

    half8 pf[2][2];   // P^T B-frags (sc2, nt), live across one iteration

    // S(tile) -> exp -> pf (+ lacc)
    auto computeS = [&](const _Float16* sKb) {
        half8 kf[4][2];
#pragma unroll
        for (int mt = 0; mt < 4; ++mt)
#pragma unroll
            for (int ks = 0; ks < 2; ++ks)
                kf[mt][ks] = *(const half8*)&sKb[(mt * 2 + ks) * 512 + lb];
#pragma unroll
        for (int sc2 = 0; sc2 < 2; ++sc2) {
            f32x4 Sa[2], Sb[2];
#pragma unroll
            for (int nt = 0; nt < 2; ++nt) {
                f32x4 t0 = __builtin_amdgcn_mfma_f32_16x16x32_f16(kf[2 * sc2][0], qb[nt][0], fz, 0, 0, 0);
                Sa[nt]   = __builtin_amdgcn_mfma_f32_16x16x32_f16(kf[2 * sc2][1], qb[nt][1], t0, 0, 0, 0);
                f32x4 t1 = __builtin_amdgcn_mfma_f32_16x16x32_f16(kf[2 * sc2 + 1][0], qb[nt][0], fz, 0, 0, 0);
                Sb[nt]   = __builtin_amdgcn_mfma_f32_16x16x32_f16(kf[2 * sc2 + 1][1], qb[nt][1], t1, 0, 0, 0);
            }
#pragma unroll
            for (int nt = 0; nt < 2; ++nt) {
                float e0 = fast_exp2(Sa[nt][0]);
                float e1 = fast_exp2(Sa[nt][1]);
                float e2 = fast_exp2(Sa[nt][2]);
                float e3 = fast_exp2(Sa[nt][3]);
                float e4 = fast_exp2(Sb[nt][0]);
                float e5 = fast_exp2(Sb[nt][1]);
                float e6 = fast_exp2(Sb[nt][2]);
                float e7 = fast_exp2(Sb[nt][3]);
                lacc[nt] += ((e0 + e1) + (e2 + e3)) + ((e4 + e5) + (e6 + e7));
                uint4 u = make_uint4(pkrtz(e0, e1), pkrtz(e2, e3),
                                     pkrtz(e4, e5), pkrtz(e6, e7));
                pf[sc2][nt] = __builtin_bit_cast(half8, u);
            }
        }
    };

    // O += V . P^T
    auto computeO = [&](const _Float16* sVb) {
        half8 vf[2][4];
#pragma unroll
        for (int sc2 = 0; sc2 < 2; ++sc2)
#pragma unroll
            for (int ct = 0; ct < 4; ++ct)
                vf[sc2][ct] = *(const half8*)&sVb[(sc2 * 4 + ct) * 512 + lb];
#pragma unroll
        for (int ct = 0; ct < 4; ++ct)
#pragma unroll
            for (int sc2 = 0; sc2 < 2; ++sc2)
#pragma unroll
                for (int nt = 0; nt < 2; ++nt)
                    Oacc[ct][nt] = __builtin_amdgcn_mfma_f32_16x16x32_f16(
                        vf[sc2][ct], pf[sc2][nt], Oacc[ct][nt], 0, 0, 0);
    };

    // ---- prologue: prime pipeline with P(0) ----
    __builtin_amdgcn_s_waitcnt(0);       // tiles 0 and 1 resident
    __syncthreads();
    computeS(sK[0]);

    // ---- main loop: 31 iterations; iteration it computes O(it), S(it+1) ----
    int bV = 0;               // buffer of tile `it` (tile t lives in buf t%3)
    for (int it = 0; it < 31; ++it) {
        __builtin_amdgcn_s_waitcnt(0);   // own prefetch (tile it+1) resident
        __syncthreads();                 // all waves: tile it+1 complete, buf(it-1) reads done
        if (it < 30) {
            int bs_ = bV + 2; if (bs_ >= 3) bs_ -= 3;
            stage(bs_, it + 2);          // overwrite buf holding tile it-1
        }
        int bK = bV + 1; if (bK >= 3) bK -= 3;
        computeO(sV[bV]);                // O(it): pf ready since last iter
        computeS(sK[bK]);                // S(it+1) -> new pf
        bV = bK;
    }

    // peeled tail: O(31). sV[bV] staged at it=29, drained at it=30's barrier;
    // no LDS writes after it=30 -> no barrier needed here.
    computeO(sV[bV]);

    // ---- epilogue: reduce lacc across quads ----
    float inv[2];
#pragma unroll
    for (int nt = 0; nt < 2; ++nt) {
        float v = lacc[nt];
        v += __shfl_xor(v, 16, 64);
        v += __shfl_xor(v, 32, 64);
        inv[nt] = 1.f / v;
    }

    float* ob = out + (((size_t)(b4 * 1024 + h * 64)) << 11) + T0 + wave * 32;
#pragma unroll
    for (int ct = 0; ct < 4; ++ct)
#pragma unroll
        for (int nt = 0; nt < 2; ++nt) {
            f32x4 o = Oacc[ct][nt];
#pragma unroll
            for (int r = 0; r < 4; ++r)
                ob[((size_t)(ct * 16 + quad * 4 + r) << 11) + nt * 16 + l15] = o[r] * inv[nt];
        }
}

extern "C" void kernel_launch(void* const* d_in, const int* in_sizes, int n_in,
                              void* d_out, int out_size, void* d_ws, size_t ws_size,
                              hipStream_t stream) {
    const float* qkv = (const float*)d_in[0];
    float* out = (float*)d_out;
    _Float16* ws = (_Float16*)d_ws;
    prep_kernel<<<dim3(4096), dim3(256), 0, stream>>>(qkv, ws);
    attn_kernel<<<dim3(512), dim3(512), 0, stream>>>(qkv, ws, out);
}